// Round 1
// baseline (1736.807 us; speedup 1.0000x reference)
//
#include <hip/hip_runtime.h>
#include <math.h>

#define NPTS 4096
#define MC   1024
#define KNB  32

typedef __attribute__((ext_vector_type(8))) short bf16x8;
typedef __attribute__((ext_vector_type(4))) float f32x4;

__device__ __forceinline__ unsigned short f2bf(float f) {
  unsigned int u = __float_as_uint(f);
  u = u + 0x7fffu + ((u >> 16) & 1u);   // round-to-nearest-even
  return (unsigned short)(u >> 16);
}

// ---------------------------------------------------------------------------
// Kernel 1: farthest point sampling. One block per batch, 1024 threads,
// 4 points per thread held in registers; points also staged in LDS so the
// winner's coords can be broadcast. Bit-exact distance: no FMA contraction.
// ---------------------------------------------------------------------------
__global__ __launch_bounds__(1024) void fps_kernel(const float* __restrict__ points,
                                                   float* __restrict__ cent_ws,
                                                   float* __restrict__ out_cent) {
  __shared__ float sx[NPTS], sy[NPTS], sz[NPTS];
  __shared__ float rv[16];
  __shared__ int   ri[16];
  __shared__ int   s_sel;
  const int b = blockIdx.x, t = threadIdx.x;
  const float* pb = points + (size_t)b * 3 * NPTS;
  float4 X = ((const float4*)pb)[t];
  float4 Y = ((const float4*)(pb + NPTS))[t];
  float4 Z = ((const float4*)(pb + 2 * NPTS))[t];
  ((float4*)sx)[t] = X; ((float4*)sy)[t] = Y; ((float4*)sz)[t] = Z;
  float fx[4] = {X.x, X.y, X.z, X.w};
  float fy[4] = {Y.x, Y.y, Y.z, Y.w};
  float fz[4] = {Z.x, Z.y, Z.z, Z.w};
  float dist[4] = {1e10f, 1e10f, 1e10f, 1e10f};
  __syncthreads();
  int last = 0;
  for (int i = 0; i < MC; ++i) {
    float lx = sx[last], ly = sy[last], lz = sz[last];
    if (t == 0) {
      out_cent[b * 3 * MC + i]          = lx;
      out_cent[b * 3 * MC + MC + i]     = ly;
      out_cent[b * 3 * MC + 2 * MC + i] = lz;
      cent_ws[(b * MC + i) * 3 + 0] = lx;
      cent_ws[(b * MC + i) * 3 + 1] = ly;
      cent_ws[(b * MC + i) * 3 + 2] = lz;
    }
    if (i == MC - 1) break;
    float bv = -1.0f; int bi = 0;
#pragma unroll
    for (int j = 0; j < 4; ++j) {
      float dx = __fsub_rn(fx[j], lx);
      float dy = __fsub_rn(fy[j], ly);
      float dz = __fsub_rn(fz[j], lz);
      float d  = __fadd_rn(__fadd_rn(__fmul_rn(dx, dx), __fmul_rn(dy, dy)), __fmul_rn(dz, dz));
      float dm = fminf(dist[j], d);
      dist[j] = dm;
      if (dm > bv) { bv = dm; bi = t * 4 + j; }   // ascending j keeps lowest idx on ties
    }
    // wave-level argmax (lowest index on ties, matching jnp.argmax)
#pragma unroll
    for (int off = 1; off < 64; off <<= 1) {
      float ov = __shfl_xor(bv, off);
      int   oi = __shfl_xor(bi, off);
      if (ov > bv || (ov == bv && oi < bi)) { bv = ov; bi = oi; }
    }
    if ((t & 63) == 0) { rv[t >> 6] = bv; ri[t >> 6] = bi; }
    __syncthreads();
    if (t < 64) {
      float v  = (t < 16) ? rv[t] : -2.0f;
      int  idx = (t < 16) ? ri[t] : 0x7fffffff;
#pragma unroll
      for (int off = 1; off < 16; off <<= 1) {
        float ov = __shfl_xor(v, off);
        int   oi = __shfl_xor(idx, off);
        if (ov > v || (ov == v && oi < idx)) { v = ov; idx = oi; }
      }
      if (t == 0) s_sel = idx;
    }
    __syncthreads();
    last = s_sel;
  }
}

// ---------------------------------------------------------------------------
// Kernel 2: features [B,64,N] fp32 -> featsT [B,N,64] bf16 (tiled transpose)
// ---------------------------------------------------------------------------
__global__ __launch_bounds__(256) void transpose_feats(const float* __restrict__ feats,
                                                       unsigned short* __restrict__ featsT) {
  __shared__ float tile[64][65];
  const int blk = blockIdx.x;
  const int b = blk >> 6;
  const int n0 = (blk & 63) * 64;
  const int t = threadIdx.x;
  const float* src = feats + (size_t)b * 64 * NPTS;
  {
    const int n = t & 63, cbase = t >> 6;
#pragma unroll
    for (int j = 0; j < 16; ++j) {
      int c = cbase + j * 4;
      tile[c][n] = src[(size_t)c * NPTS + n0 + n];
    }
  }
  __syncthreads();
  {
    const int c = t & 63, nbase = t >> 6;
    unsigned short* dst = featsT + ((size_t)b * NPTS + n0) * 64;
#pragma unroll
    for (int j = 0; j < 16; ++j) {
      int n = nbase + j * 4;
      dst[(size_t)n * 64 + c] = f2bf(tile[c][n]);
    }
  }
}

// ---------------------------------------------------------------------------
// Kernel 3: pack W1/W2/W3 into MFMA B-fragment order (bf16), with the layer-1
// column remap: X cols 0..63 = gfeat (ref cols 3..66), 64..66 = local xyz,
// 67..95 = zero pad. Frag f holds B[k][n], lane l: n = nt*16+(l&15),
// k = kt*32+(l>>4)*8+j.
// ---------------------------------------------------------------------------
__global__ __launch_bounds__(64) void pack_w(const float* __restrict__ w1,
                                             const float* __restrict__ w2,
                                             const float* __restrict__ w3,
                                             unsigned short* __restrict__ wpack) {
  const int f = blockIdx.x, lane = threadIdx.x;
  int layer, kt, nt;
  if (f < 12)      { layer = 0; kt = f >> 2;        nt = f & 3; }
  else if (f < 20) { layer = 1; kt = (f - 12) >> 2; nt = (f - 12) & 3; }
  else             { layer = 2; kt = (f - 20) >> 3; nt = (f - 20) & 7; }
  const int o = nt * 16 + (lane & 15);
  unsigned short* dst = wpack + ((size_t)f * 64 + lane) * 8;
#pragma unroll
  for (int j = 0; j < 8; ++j) {
    int k = kt * 32 + (lane >> 4) * 8 + j;
    float x = 0.0f;
    if (layer == 0)      { if (k < 67) { int cin = (k < 64) ? (k + 3) : (k - 64); x = w1[o * 67 + cin]; } }
    else if (layer == 1) { x = w2[o * 64 + k]; }
    else                 { x = w3[o * 64 + k]; }
    dst[j] = f2bf(x);
  }
}

// ---------------------------------------------------------------------------
// Kernel 4: ball query. 16 blocks per batch; block stages all points in LDS;
// each wave handles 16 centroids; first-K-by-index collection via 64-bit
// ballot; pad with first hit. Bit-exact d2 = (c2+p2) - 2*dot.
// ---------------------------------------------------------------------------
__global__ __launch_bounds__(256) void ball_query_kernel(const float* __restrict__ points,
                                                         const float* __restrict__ cent_ws,
                                                         int* __restrict__ nidx) {
  __shared__ float sx[NPTS], sy[NPTS], sz[NPTS];
  __shared__ int lists[4][KNB];
  const int b  = blockIdx.x >> 4;
  const int cb = blockIdx.x & 15;
  const int t = threadIdx.x;
  const float* pb = points + (size_t)b * 3 * NPTS;
#pragma unroll
  for (int j = 0; j < 4; ++j) {
    int i4 = t + j * 256;
    ((float4*)sx)[i4] = ((const float4*)pb)[i4];
    ((float4*)sy)[i4] = ((const float4*)(pb + NPTS))[i4];
    ((float4*)sz)[i4] = ((const float4*)(pb + 2 * NPTS))[i4];
  }
  __syncthreads();
  const int w = t >> 6, lane = t & 63;
  const float R2 = (float)(0.2 * 0.2);
  for (int cm = 0; cm < 16; ++cm) {
    const int m  = cb * 64 + w * 16 + cm;
    const int bm = b * MC + m;
    const float cx = cent_ws[bm * 3 + 0], cy = cent_ws[bm * 3 + 1], cz = cent_ws[bm * 3 + 2];
    const float c2 = __fadd_rn(__fadd_rn(__fmul_rn(cx, cx), __fmul_rn(cy, cy)), __fmul_rn(cz, cz));
    int cnt = 0;
    for (int ch = 0; ch < 64; ++ch) {
      const int n = ch * 64 + lane;
      float x = sx[n], y = sy[n], z = sz[n];
      float p2  = __fadd_rn(__fadd_rn(__fmul_rn(x, x),  __fmul_rn(y, y)),  __fmul_rn(z, z));
      float dot = __fadd_rn(__fadd_rn(__fmul_rn(cx, x), __fmul_rn(cy, y)), __fmul_rn(cz, z));
      float d2  = __fsub_rn(__fadd_rn(c2, p2), __fmul_rn(2.0f, dot));
      bool hit = (d2 <= R2);
      unsigned long long msk = __ballot(hit);
      if (hit) {
        int pos = cnt + __popcll(msk & ((1ull << lane) - 1ull));
        if (pos < KNB) lists[w][pos] = n;
      }
      cnt += __popcll(msk);
      if (cnt >= KNB) break;
    }
    if (lane < KNB) {
      int first = lists[w][0];
      int v = (lane < cnt) ? lists[w][lane] : first;
      nidx[(size_t)bm * KNB + lane] = v;
    }
  }
}

// ---------------------------------------------------------------------------
// Kernel 5: fused gather + 3-layer MLP (bf16 MFMA 16x16x32) + maxpool.
// One wave per centroid, 4 centroids per wave (16 per block). Layer-1 A-frags
// load straight from featsT (8 contiguous bf16 per lane); local-xyz synthesized
// in registers as the kt=2 fragment. Inter-layer transform via per-wave LDS.
// ---------------------------------------------------------------------------
__global__ __launch_bounds__(256) void mlp_kernel(
    const float* __restrict__ points,
    const float* __restrict__ cent_ws,
    const int* __restrict__ nidx,
    const unsigned short* __restrict__ featsT,
    const unsigned short* __restrict__ wpack,
    const float* __restrict__ b1, const float* __restrict__ g1, const float* __restrict__ be1,
    const float* __restrict__ b2, const float* __restrict__ g2, const float* __restrict__ be2,
    const float* __restrict__ b3, const float* __restrict__ g3, const float* __restrict__ be3,
    float* __restrict__ out) {
  __shared__ __align__(16) unsigned short Hs[4][2][32 * 72];
  __shared__ float obuf[128 * 16];
  const int t = threadIdx.x;
  const int w = t >> 6, lane = t & 63;
  const int r = lane & 15, q = lane >> 4;
  const float inv_s = 1.0f / sqrtf(1.0f + 1e-5f);

  float pb1[4], ps1[4], pe1[4], pb2[4], ps2[4], pe2[4], pb3[8], ps3[8], pe3[8];
#pragma unroll
  for (int nt = 0; nt < 4; ++nt) {
    int o = nt * 16 + r;
    pb1[nt] = b1[o]; ps1[nt] = g1[o] * inv_s; pe1[nt] = be1[o];
    pb2[nt] = b2[o]; ps2[nt] = g2[o] * inv_s; pe2[nt] = be2[o];
  }
#pragma unroll
  for (int nt = 0; nt < 8; ++nt) {
    int o = nt * 16 + r;
    pb3[nt] = b3[o]; ps3[nt] = g3[o] * inv_s; pe3[nt] = be3[o];
  }
  const int bm0 = blockIdx.x * 16;
  const int b   = bm0 >> 10;
  const int m0  = bm0 & 1023;
  const float* ptsb = points + (size_t)b * 3 * NPTS;

  for (int it = 0; it < 4; ++it) {
    const int ml = it * 4 + w;
    const int bm = bm0 + ml;
    const int n0 = nidx[(size_t)bm * KNB + r];
    const int n1 = nidx[(size_t)bm * KNB + 16 + r];
    const float cx = cent_ws[bm * 3 + 0], cy = cent_ws[bm * 3 + 1], cz = cent_ws[bm * 3 + 2];

    // ---- layer 1 ----
    bf16x8 aF[2][2];
#pragma unroll
    for (int mt = 0; mt < 2; ++mt) {
      int n = mt ? n1 : n0;
      const unsigned short* rowp = featsT + ((size_t)b * NPTS + n) * 64 + q * 8;
      aF[mt][0] = *(const bf16x8*)(rowp);
      aF[mt][1] = *(const bf16x8*)(rowp + 32);
    }
    bf16x8 aL[2];
#pragma unroll
    for (int mt = 0; mt < 2; ++mt) {
      bf16x8 a = {0, 0, 0, 0, 0, 0, 0, 0};
      if (q == 0) {
        int n = mt ? n1 : n0;
        a[0] = (short)f2bf(ptsb[n] - cx);
        a[1] = (short)f2bf(ptsb[NPTS + n] - cy);
        a[2] = (short)f2bf(ptsb[2 * NPTS + n] - cz);
      }
      aL[mt] = a;
    }
    f32x4 acc1[2][4];
#pragma unroll
    for (int mt = 0; mt < 2; ++mt)
#pragma unroll
      for (int nt = 0; nt < 4; ++nt) acc1[mt][nt] = (f32x4){0.f, 0.f, 0.f, 0.f};
#pragma unroll
    for (int kt = 0; kt < 3; ++kt) {
#pragma unroll
      for (int nt = 0; nt < 4; ++nt) {
        bf16x8 wf = *(const bf16x8*)(wpack + ((size_t)(kt * 4 + nt) * 64 + lane) * 8);
#pragma unroll
        for (int mt = 0; mt < 2; ++mt) {
          bf16x8 a = (kt < 2) ? aF[mt][kt] : aL[mt];
          acc1[mt][nt] = __builtin_amdgcn_mfma_f32_16x16x32_bf16(a, wf, acc1[mt][nt], 0, 0, 0);
        }
      }
    }
#pragma unroll
    for (int mt = 0; mt < 2; ++mt)
#pragma unroll
      for (int nt = 0; nt < 4; ++nt)
#pragma unroll
        for (int rr = 0; rr < 4; ++rr) {
          float y = (acc1[mt][nt][rr] + pb1[nt]) * ps1[nt] + pe1[nt];
          y = fmaxf(y, 0.0f);
          Hs[w][0][(mt * 16 + q * 4 + rr) * 72 + nt * 16 + r] = f2bf(y);
        }
    __syncthreads();

    // ---- layer 2 ----
    f32x4 acc2[2][4];
#pragma unroll
    for (int mt = 0; mt < 2; ++mt)
#pragma unroll
      for (int nt = 0; nt < 4; ++nt) acc2[mt][nt] = (f32x4){0.f, 0.f, 0.f, 0.f};
#pragma unroll
    for (int kt = 0; kt < 2; ++kt) {
      bf16x8 a0 = *(const bf16x8*)&Hs[w][0][(0 * 16 + r) * 72 + kt * 32 + q * 8];
      bf16x8 a1 = *(const bf16x8*)&Hs[w][0][(1 * 16 + r) * 72 + kt * 32 + q * 8];
#pragma unroll
      for (int nt = 0; nt < 4; ++nt) {
        bf16x8 wf = *(const bf16x8*)(wpack + ((size_t)(12 + kt * 4 + nt) * 64 + lane) * 8);
        acc2[0][nt] = __builtin_amdgcn_mfma_f32_16x16x32_bf16(a0, wf, acc2[0][nt], 0, 0, 0);
        acc2[1][nt] = __builtin_amdgcn_mfma_f32_16x16x32_bf16(a1, wf, acc2[1][nt], 0, 0, 0);
      }
    }
#pragma unroll
    for (int mt = 0; mt < 2; ++mt)
#pragma unroll
      for (int nt = 0; nt < 4; ++nt)
#pragma unroll
        for (int rr = 0; rr < 4; ++rr) {
          float y = (acc2[mt][nt][rr] + pb2[nt]) * ps2[nt] + pe2[nt];
          y = fmaxf(y, 0.0f);
          Hs[w][1][(mt * 16 + q * 4 + rr) * 72 + nt * 16 + r] = f2bf(y);
        }
    __syncthreads();

    // ---- layer 3 + maxpool ----
    f32x4 acc3[2][8];
#pragma unroll
    for (int mt = 0; mt < 2; ++mt)
#pragma unroll
      for (int nt = 0; nt < 8; ++nt) acc3[mt][nt] = (f32x4){0.f, 0.f, 0.f, 0.f};
#pragma unroll
    for (int kt = 0; kt < 2; ++kt) {
      bf16x8 a0 = *(const bf16x8*)&Hs[w][1][(0 * 16 + r) * 72 + kt * 32 + q * 8];
      bf16x8 a1 = *(const bf16x8*)&Hs[w][1][(1 * 16 + r) * 72 + kt * 32 + q * 8];
#pragma unroll
      for (int nt = 0; nt < 8; ++nt) {
        bf16x8 wf = *(const bf16x8*)(wpack + ((size_t)(20 + kt * 8 + nt) * 64 + lane) * 8);
        acc3[0][nt] = __builtin_amdgcn_mfma_f32_16x16x32_bf16(a0, wf, acc3[0][nt], 0, 0, 0);
        acc3[1][nt] = __builtin_amdgcn_mfma_f32_16x16x32_bf16(a1, wf, acc3[1][nt], 0, 0, 0);
      }
    }
#pragma unroll
    for (int nt = 0; nt < 8; ++nt) {
      float pm = 0.0f;   // relu outputs are >= 0
#pragma unroll
      for (int mt = 0; mt < 2; ++mt)
#pragma unroll
        for (int rr = 0; rr < 4; ++rr) {
          float y = (acc3[mt][nt][rr] + pb3[nt]) * ps3[nt] + pe3[nt];
          y = fmaxf(y, 0.0f);
          pm = fmaxf(pm, y);
        }
      pm = fmaxf(pm, __shfl_xor(pm, 16));
      pm = fmaxf(pm, __shfl_xor(pm, 32));
      if (q == 0) obuf[(nt * 16 + r) * 16 + ml] = pm;
    }
  }
  __syncthreads();
  float* outp = out + (size_t)b * 128 * 1024 + m0;
#pragma unroll
  for (int i = 0; i < 8; ++i) {
    int idx = t + i * 256;
    outp[(size_t)(idx >> 4) * 1024 + (idx & 15)] = obuf[idx];
  }
}

// ---------------------------------------------------------------------------
extern "C" void kernel_launch(void* const* d_in, const int* in_sizes, int n_in,
                              void* d_out, int out_size, void* d_ws, size_t ws_size,
                              hipStream_t stream) {
  (void)in_sizes; (void)n_in; (void)out_size; (void)ws_size;
  const float* points   = (const float*)d_in[0];
  const float* features = (const float*)d_in[1];
  const float* w1  = (const float*)d_in[2];
  const float* b1  = (const float*)d_in[3];
  const float* g1  = (const float*)d_in[4];
  const float* be1 = (const float*)d_in[5];
  const float* w2  = (const float*)d_in[6];
  const float* b2  = (const float*)d_in[7];
  const float* g2  = (const float*)d_in[8];
  const float* be2 = (const float*)d_in[9];
  const float* w3  = (const float*)d_in[10];
  const float* b3  = (const float*)d_in[11];
  const float* g3  = (const float*)d_in[12];
  const float* be3 = (const float*)d_in[13];

  float* outc = (float*)d_out;                  // centroids [16,3,1024]
  float* outf = outc + 16 * 3 * 1024;           // features  [16,128,1024]

  char* ws = (char*)d_ws;
  float*          cent_ws = (float*)(ws);                    // 16384*3*4   = 196608 B
  int*            nidx    = (int*)(ws + 0x40000);            // 16384*32*4  = 2 MiB
  unsigned short* featsT  = (unsigned short*)(ws + 0x240000);// 16*4096*64*2= 8 MiB
  unsigned short* wpack   = (unsigned short*)(ws + 0xA40000);// 36*1024 B

  fps_kernel<<<16, 1024, 0, stream>>>(points, cent_ws, outc);
  transpose_feats<<<1024, 256, 0, stream>>>(features, featsT);
  pack_w<<<36, 64, 0, stream>>>(w1, w2, w3, wpack);
  ball_query_kernel<<<256, 256, 0, stream>>>(points, cent_ws, nidx);
  mlp_kernel<<<1024, 256, 0, stream>>>(points, cent_ws, nidx, featsT, wpack,
                                       b1, g1, be1, b2, g2, be2, b3, g3, be3, outf);
}

// Round 2
// 1480.980 us; speedup vs baseline: 1.1727x; 1.1727x over previous
//
#include <hip/hip_runtime.h>
#include <math.h>

#define NPTS 4096
#define MC   1024
#define KNB  32

typedef __attribute__((ext_vector_type(8))) short bf16x8;
typedef __attribute__((ext_vector_type(4))) float f32x4;

__device__ __forceinline__ unsigned short f2bf(float f) {
  unsigned int u = __float_as_uint(f);
  u = u + 0x7fffu + ((u >> 16) & 1u);   // round-to-nearest-even
  return (unsigned short)(u >> 16);
}

// DPP-based wave64 argmax step: combine with lane shifted by CTRL.
// Keeps greater value; on exact tie keeps lower index.
template <int CTRL>
__device__ __forceinline__ void dpp_step(float& bv, int& bi) {
  int vb = __float_as_int(bv);
  int ov = __builtin_amdgcn_update_dpp(vb, vb, CTRL, 0xF, 0xF, false);
  int oi = __builtin_amdgcn_update_dpp(bi, bi, CTRL, 0xF, 0xF, false);
  float ovf = __int_as_float(ov);
  if (ovf > bv || (ovf == bv && oi < bi)) { bv = ovf; bi = oi; }
}

// ---------------------------------------------------------------------------
// Kernel 1: farthest point sampling. One block per batch, 512 threads,
// 8 points per thread in registers. Per iteration: read winning candidate
// (value+coords) from LDS slots, update dists, DPP wave argmax, owner lane
// publishes (value,coords) to its wave's slot. ONE barrier per iteration.
// Bit-exact distances (no FMA contraction).
// ---------------------------------------------------------------------------
__global__ __launch_bounds__(512) void fps_kernel(const float* __restrict__ points,
                                                  float* __restrict__ out_cent) {
  __shared__ __align__(16) float  sval[2][8];
  __shared__ __align__(16) float4 scoord[2][8];
  __shared__ float slog[3][MC];
  const int b = blockIdx.x, t = threadIdx.x;
  const int w = t >> 6;
  const int t8 = t * 8;
  const float* pb = points + (size_t)b * 3 * NPTS;

  float fx[8], fy[8], fz[8], dist[8];
  {
    const float4* px = (const float4*)pb;
    const float4* py = (const float4*)(pb + NPTS);
    const float4* pz = (const float4*)(pb + 2 * NPTS);
    float4 a0 = px[t * 2], a1 = px[t * 2 + 1];
    float4 b0 = py[t * 2], b1 = py[t * 2 + 1];
    float4 c0 = pz[t * 2], c1 = pz[t * 2 + 1];
    fx[0] = a0.x; fx[1] = a0.y; fx[2] = a0.z; fx[3] = a0.w;
    fx[4] = a1.x; fx[5] = a1.y; fx[6] = a1.z; fx[7] = a1.w;
    fy[0] = b0.x; fy[1] = b0.y; fy[2] = b0.z; fy[3] = b0.w;
    fy[4] = b1.x; fy[5] = b1.y; fy[6] = b1.z; fy[7] = b1.w;
    fz[0] = c0.x; fz[1] = c0.y; fz[2] = c0.z; fz[3] = c0.w;
    fz[4] = c1.x; fz[5] = c1.y; fz[6] = c1.z; fz[7] = c1.w;
  }
#pragma unroll
  for (int j = 0; j < 8; ++j) dist[j] = 1e10f;

  // first centroid = point 0 (uniform scalar loads)
  float lx = pb[0], ly = pb[NPTS], lz = pb[2 * NPTS];

  for (int i = 0; i < MC; ++i) {
    if (t == 0) { slog[0][i] = lx; slog[1][i] = ly; slog[2][i] = lz; }
    if (i == MC - 1) break;

    // distance update + per-lane argmax over 8 owned points
    float bv = -1.0f; int bi = 0;
#pragma unroll
    for (int j = 0; j < 8; ++j) {
      float dx = __fsub_rn(fx[j], lx);
      float dy = __fsub_rn(fy[j], ly);
      float dz = __fsub_rn(fz[j], lz);
      float d  = __fadd_rn(__fadd_rn(__fmul_rn(dx, dx), __fmul_rn(dy, dy)), __fmul_rn(dz, dz));
      float dm = fminf(dist[j], d);
      dist[j] = dm;
      if (dm > bv) { bv = dm; bi = t8 + j; }   // ascending j: lowest idx on ties
    }

    // wave64 argmax via DPP (result lands in lane 63)
    dpp_step<0x111>(bv, bi);   // row_shr:1
    dpp_step<0x112>(bv, bi);   // row_shr:2
    dpp_step<0x114>(bv, bi);   // row_shr:4
    dpp_step<0x118>(bv, bi);   // row_shr:8
    dpp_step<0x142>(bv, bi);   // row_bcast:15
    dpp_step<0x143>(bv, bi);   // row_bcast:31
    const int   sel = __builtin_amdgcn_readlane(bi, 63);
    const float wv  = __int_as_float(__builtin_amdgcn_readlane(__float_as_int(bv), 63));

    const int nb = i & 1;
    // owning thread publishes value + coords of its wave's candidate
    if ((sel >> 3) == t) {
      float ox = fx[0], oy = fy[0], oz = fz[0];
#pragma unroll
      for (int j = 1; j < 8; ++j) {
        if ((sel & 7) == j) { ox = fx[j]; oy = fy[j]; oz = fz[j]; }
      }
      sval[nb][w]   = wv;
      scoord[nb][w] = make_float4(ox, oy, oz, 0.0f);
    }
    __syncthreads();

    // every thread reduces the 8 wave candidates. Wave w owns indices
    // [w*512,(w+1)*512): ascending scan + strict '>' == lowest-index tie-break.
    float4 va = ((const float4*)sval[nb])[0];
    float4 vb2 = ((const float4*)sval[nb])[1];
    float v[8] = {va.x, va.y, va.z, va.w, vb2.x, vb2.y, vb2.z, vb2.w};
    int ws = 0; float bval = v[0];
#pragma unroll
    for (int k = 1; k < 8; ++k) {
      if (v[k] > bval) { bval = v[k]; ws = k; }
    }
    float4 c = scoord[nb][ws];
    lx = c.x; ly = c.y; lz = c.z;
  }
  __syncthreads();
  // coalesced centroid output [3][1024] per batch
  float* oc = out_cent + (size_t)b * 3 * MC;
#pragma unroll
  for (int k = 0; k < 6; ++k) {
    int idx = t + k * 512;
    oc[idx] = ((const float*)slog)[idx];
  }
}

// ---------------------------------------------------------------------------
// Kernel 2: features [B,64,N] fp32 -> featsT [B,N,64] bf16 (tiled transpose)
// ---------------------------------------------------------------------------
__global__ __launch_bounds__(256) void transpose_feats(const float* __restrict__ feats,
                                                       unsigned short* __restrict__ featsT) {
  __shared__ float tile[64][65];
  const int blk = blockIdx.x;
  const int b = blk >> 6;
  const int n0 = (blk & 63) * 64;
  const int t = threadIdx.x;
  const float* src = feats + (size_t)b * 64 * NPTS;
  {
    const int n = t & 63, cbase = t >> 6;
#pragma unroll
    for (int j = 0; j < 16; ++j) {
      int c = cbase + j * 4;
      tile[c][n] = src[(size_t)c * NPTS + n0 + n];
    }
  }
  __syncthreads();
  {
    const int c = t & 63, nbase = t >> 6;
    unsigned short* dst = featsT + ((size_t)b * NPTS + n0) * 64;
#pragma unroll
    for (int j = 0; j < 16; ++j) {
      int n = nbase + j * 4;
      dst[(size_t)n * 64 + c] = f2bf(tile[c][n]);
    }
  }
}

// ---------------------------------------------------------------------------
// Kernel 3: pack W1/W2/W3 into MFMA B-fragment order (bf16), with the layer-1
// column remap: X cols 0..63 = gfeat (ref cols 3..66), 64..66 = local xyz,
// 67..95 = zero pad.
// ---------------------------------------------------------------------------
__global__ __launch_bounds__(64) void pack_w(const float* __restrict__ w1,
                                             const float* __restrict__ w2,
                                             const float* __restrict__ w3,
                                             unsigned short* __restrict__ wpack) {
  const int f = blockIdx.x, lane = threadIdx.x;
  int layer, kt, nt;
  if (f < 12)      { layer = 0; kt = f >> 2;        nt = f & 3; }
  else if (f < 20) { layer = 1; kt = (f - 12) >> 2; nt = (f - 12) & 3; }
  else             { layer = 2; kt = (f - 20) >> 3; nt = (f - 20) & 7; }
  const int o = nt * 16 + (lane & 15);
  unsigned short* dst = wpack + ((size_t)f * 64 + lane) * 8;
#pragma unroll
  for (int j = 0; j < 8; ++j) {
    int k = kt * 32 + (lane >> 4) * 8 + j;
    float x = 0.0f;
    if (layer == 0)      { if (k < 67) { int cin = (k < 64) ? (k + 3) : (k - 64); x = w1[o * 67 + cin]; } }
    else if (layer == 1) { x = w2[o * 64 + k]; }
    else                 { x = w3[o * 64 + k]; }
    dst[j] = f2bf(x);
  }
}

// ---------------------------------------------------------------------------
// Kernel 4: ball query. Centroids read from out_cent layout [B,3,MC].
// ---------------------------------------------------------------------------
__global__ __launch_bounds__(256) void ball_query_kernel(const float* __restrict__ points,
                                                         const float* __restrict__ cent,
                                                         int* __restrict__ nidx) {
  __shared__ float sx[NPTS], sy[NPTS], sz[NPTS];
  __shared__ int lists[4][KNB];
  const int b  = blockIdx.x >> 4;
  const int cb = blockIdx.x & 15;
  const int t = threadIdx.x;
  const float* pb = points + (size_t)b * 3 * NPTS;
#pragma unroll
  for (int j = 0; j < 4; ++j) {
    int i4 = t + j * 256;
    ((float4*)sx)[i4] = ((const float4*)pb)[i4];
    ((float4*)sy)[i4] = ((const float4*)(pb + NPTS))[i4];
    ((float4*)sz)[i4] = ((const float4*)(pb + 2 * NPTS))[i4];
  }
  __syncthreads();
  const int w = t >> 6, lane = t & 63;
  const float R2 = (float)(0.2 * 0.2);
  const float* cbp = cent + (size_t)b * 3 * MC;
  for (int cm = 0; cm < 16; ++cm) {
    const int m  = cb * 64 + w * 16 + cm;
    const int bm = b * MC + m;
    const float cx = cbp[m], cy = cbp[MC + m], cz = cbp[2 * MC + m];
    const float c2 = __fadd_rn(__fadd_rn(__fmul_rn(cx, cx), __fmul_rn(cy, cy)), __fmul_rn(cz, cz));
    int cnt = 0;
    for (int ch = 0; ch < 64; ++ch) {
      const int n = ch * 64 + lane;
      float x = sx[n], y = sy[n], z = sz[n];
      float p2  = __fadd_rn(__fadd_rn(__fmul_rn(x, x),  __fmul_rn(y, y)),  __fmul_rn(z, z));
      float dot = __fadd_rn(__fadd_rn(__fmul_rn(cx, x), __fmul_rn(cy, y)), __fmul_rn(cz, z));
      float d2  = __fsub_rn(__fadd_rn(c2, p2), __fmul_rn(2.0f, dot));
      bool hit = (d2 <= R2);
      unsigned long long msk = __ballot(hit);
      if (hit) {
        int pos = cnt + __popcll(msk & ((1ull << lane) - 1ull));
        if (pos < KNB) lists[w][pos] = n;
      }
      cnt += __popcll(msk);
      if (cnt >= KNB) break;
    }
    if (lane < KNB) {
      int first = lists[w][0];
      int v = (lane < cnt) ? lists[w][lane] : first;
      nidx[(size_t)bm * KNB + lane] = v;
    }
  }
}

// ---------------------------------------------------------------------------
// Kernel 5: fused gather + 3-layer MLP (bf16 MFMA 16x16x32) + maxpool.
// Hs is wave-private: no block barriers between layers, only
// __threadfence_block() (lockstep wave64 makes cross-lane LDS RAW safe once
// ordered + lgkm-drained). obuf stride 20 kills the 16-way bank conflict.
// ---------------------------------------------------------------------------
__global__ __launch_bounds__(256) void mlp_kernel(
    const float* __restrict__ points,
    const float* __restrict__ cent,
    const int* __restrict__ nidx,
    const unsigned short* __restrict__ featsT,
    const unsigned short* __restrict__ wpack,
    const float* __restrict__ b1, const float* __restrict__ g1, const float* __restrict__ be1,
    const float* __restrict__ b2, const float* __restrict__ g2, const float* __restrict__ be2,
    const float* __restrict__ b3, const float* __restrict__ g3, const float* __restrict__ be3,
    float* __restrict__ out) {
  __shared__ __align__(16) unsigned short Hs[4][2][32 * 72];
  __shared__ __align__(16) float obuf[128 * 20];
  const int t = threadIdx.x;
  const int w = t >> 6, lane = t & 63;
  const int r = lane & 15, q = lane >> 4;
  const float inv_s = 1.0f / sqrtf(1.0f + 1e-5f);

  float pb1[4], ps1[4], pe1[4], pb2[4], ps2[4], pe2[4], pb3[8], ps3[8], pe3[8];
#pragma unroll
  for (int nt = 0; nt < 4; ++nt) {
    int o = nt * 16 + r;
    pb1[nt] = b1[o]; ps1[nt] = g1[o] * inv_s; pe1[nt] = be1[o];
    pb2[nt] = b2[o]; ps2[nt] = g2[o] * inv_s; pe2[nt] = be2[o];
  }
#pragma unroll
  for (int nt = 0; nt < 8; ++nt) {
    int o = nt * 16 + r;
    pb3[nt] = b3[o]; ps3[nt] = g3[o] * inv_s; pe3[nt] = be3[o];
  }
  const int bm0 = blockIdx.x * 16;
  const int b   = bm0 >> 10;
  const int m0  = bm0 & 1023;
  const float* ptsb = points + (size_t)b * 3 * NPTS;
  const float* cbp  = cent + (size_t)b * 3 * MC;

  for (int it = 0; it < 4; ++it) {
    const int ml = it * 4 + w;
    const int bm = bm0 + ml;
    const int m  = bm & 1023;
    const int n0 = nidx[(size_t)bm * KNB + r];
    const int n1 = nidx[(size_t)bm * KNB + 16 + r];
    const float cx = cbp[m], cy = cbp[MC + m], cz = cbp[2 * MC + m];

    // ---- layer 1 ----
    bf16x8 aF[2][2];
#pragma unroll
    for (int mt = 0; mt < 2; ++mt) {
      int n = mt ? n1 : n0;
      const unsigned short* rowp = featsT + ((size_t)b * NPTS + n) * 64 + q * 8;
      aF[mt][0] = *(const bf16x8*)(rowp);
      aF[mt][1] = *(const bf16x8*)(rowp + 32);
    }
    bf16x8 aL[2];
#pragma unroll
    for (int mt = 0; mt < 2; ++mt) {
      bf16x8 a = {0, 0, 0, 0, 0, 0, 0, 0};
      if (q == 0) {
        int n = mt ? n1 : n0;
        a[0] = (short)f2bf(ptsb[n] - cx);
        a[1] = (short)f2bf(ptsb[NPTS + n] - cy);
        a[2] = (short)f2bf(ptsb[2 * NPTS + n] - cz);
      }
      aL[mt] = a;
    }
    f32x4 acc1[2][4];
#pragma unroll
    for (int mt = 0; mt < 2; ++mt)
#pragma unroll
      for (int nt = 0; nt < 4; ++nt) acc1[mt][nt] = (f32x4){0.f, 0.f, 0.f, 0.f};
#pragma unroll
    for (int kt = 0; kt < 3; ++kt) {
#pragma unroll
      for (int nt = 0; nt < 4; ++nt) {
        bf16x8 wf = *(const bf16x8*)(wpack + ((size_t)(kt * 4 + nt) * 64 + lane) * 8);
#pragma unroll
        for (int mt = 0; mt < 2; ++mt) {
          bf16x8 a = (kt < 2) ? aF[mt][kt] : aL[mt];
          acc1[mt][nt] = __builtin_amdgcn_mfma_f32_16x16x32_bf16(a, wf, acc1[mt][nt], 0, 0, 0);
        }
      }
    }
#pragma unroll
    for (int mt = 0; mt < 2; ++mt)
#pragma unroll
      for (int nt = 0; nt < 4; ++nt)
#pragma unroll
        for (int rr = 0; rr < 4; ++rr) {
          float y = (acc1[mt][nt][rr] + pb1[nt]) * ps1[nt] + pe1[nt];
          y = fmaxf(y, 0.0f);
          Hs[w][0][(mt * 16 + q * 4 + rr) * 72 + nt * 16 + r] = f2bf(y);
        }
    __threadfence_block();

    // ---- layer 2 ----
    f32x4 acc2[2][4];
#pragma unroll
    for (int mt = 0; mt < 2; ++mt)
#pragma unroll
      for (int nt = 0; nt < 4; ++nt) acc2[mt][nt] = (f32x4){0.f, 0.f, 0.f, 0.f};
#pragma unroll
    for (int kt = 0; kt < 2; ++kt) {
      bf16x8 a0 = *(const bf16x8*)&Hs[w][0][(0 * 16 + r) * 72 + kt * 32 + q * 8];
      bf16x8 a1 = *(const bf16x8*)&Hs[w][0][(1 * 16 + r) * 72 + kt * 32 + q * 8];
#pragma unroll
      for (int nt = 0; nt < 4; ++nt) {
        bf16x8 wf = *(const bf16x8*)(wpack + ((size_t)(12 + kt * 4 + nt) * 64 + lane) * 8);
        acc2[0][nt] = __builtin_amdgcn_mfma_f32_16x16x32_bf16(a0, wf, acc2[0][nt], 0, 0, 0);
        acc2[1][nt] = __builtin_amdgcn_mfma_f32_16x16x32_bf16(a1, wf, acc2[1][nt], 0, 0, 0);
      }
    }
#pragma unroll
    for (int mt = 0; mt < 2; ++mt)
#pragma unroll
      for (int nt = 0; nt < 4; ++nt)
#pragma unroll
        for (int rr = 0; rr < 4; ++rr) {
          float y = (acc2[mt][nt][rr] + pb2[nt]) * ps2[nt] + pe2[nt];
          y = fmaxf(y, 0.0f);
          Hs[w][1][(mt * 16 + q * 4 + rr) * 72 + nt * 16 + r] = f2bf(y);
        }
    __threadfence_block();

    // ---- layer 3 + maxpool ----
    f32x4 acc3[2][8];
#pragma unroll
    for (int mt = 0; mt < 2; ++mt)
#pragma unroll
      for (int nt = 0; nt < 8; ++nt) acc3[mt][nt] = (f32x4){0.f, 0.f, 0.f, 0.f};
#pragma unroll
    for (int kt = 0; kt < 2; ++kt) {
      bf16x8 a0 = *(const bf16x8*)&Hs[w][1][(0 * 16 + r) * 72 + kt * 32 + q * 8];
      bf16x8 a1 = *(const bf16x8*)&Hs[w][1][(1 * 16 + r) * 72 + kt * 32 + q * 8];
#pragma unroll
      for (int nt = 0; nt < 8; ++nt) {
        bf16x8 wf = *(const bf16x8*)(wpack + ((size_t)(20 + kt * 8 + nt) * 64 + lane) * 8);
        acc3[0][nt] = __builtin_amdgcn_mfma_f32_16x16x32_bf16(a0, wf, acc3[0][nt], 0, 0, 0);
        acc3[1][nt] = __builtin_amdgcn_mfma_f32_16x16x32_bf16(a1, wf, acc3[1][nt], 0, 0, 0);
      }
    }
#pragma unroll
    for (int nt = 0; nt < 8; ++nt) {
      float pm = 0.0f;   // relu outputs are >= 0
#pragma unroll
      for (int mt = 0; mt < 2; ++mt)
#pragma unroll
        for (int rr = 0; rr < 4; ++rr) {
          float y = (acc3[mt][nt][rr] + pb3[nt]) * ps3[nt] + pe3[nt];
          y = fmaxf(y, 0.0f);
          pm = fmaxf(pm, y);
        }
      pm = fmaxf(pm, __shfl_xor(pm, 16));
      pm = fmaxf(pm, __shfl_xor(pm, 32));
      if (q == 0) obuf[(nt * 16 + r) * 20 + ml] = pm;
    }
    __threadfence_block();
  }
  __syncthreads();
  // coalesced-ish store: thread t -> channel t>>1, half (t&1)*8
  {
    const int ch = t >> 1, mh = (t & 1) * 8;
    float4 u0 = *(const float4*)&obuf[ch * 20 + mh];
    float4 u1 = *(const float4*)&obuf[ch * 20 + mh + 4];
    float* outp = out + ((size_t)b * 128 + ch) * 1024 + m0 + mh;
    *(float4*)(outp)     = u0;
    *(float4*)(outp + 4) = u1;
  }
}

// ---------------------------------------------------------------------------
extern "C" void kernel_launch(void* const* d_in, const int* in_sizes, int n_in,
                              void* d_out, int out_size, void* d_ws, size_t ws_size,
                              hipStream_t stream) {
  (void)in_sizes; (void)n_in; (void)out_size; (void)ws_size;
  const float* points   = (const float*)d_in[0];
  const float* features = (const float*)d_in[1];
  const float* w1  = (const float*)d_in[2];
  const float* b1  = (const float*)d_in[3];
  const float* g1  = (const float*)d_in[4];
  const float* be1 = (const float*)d_in[5];
  const float* w2  = (const float*)d_in[6];
  const float* b2  = (const float*)d_in[7];
  const float* g2  = (const float*)d_in[8];
  const float* be2 = (const float*)d_in[9];
  const float* w3  = (const float*)d_in[10];
  const float* b3  = (const float*)d_in[11];
  const float* g3  = (const float*)d_in[12];
  const float* be3 = (const float*)d_in[13];

  float* outc = (float*)d_out;                  // centroids [16,3,1024]
  float* outf = outc + 16 * 3 * 1024;           // features  [16,128,1024]

  char* ws = (char*)d_ws;
  int*            nidx    = (int*)(ws);                      // 16384*32*4  = 2 MiB
  unsigned short* featsT  = (unsigned short*)(ws + 0x200000);// 16*4096*64*2= 8 MiB
  unsigned short* wpack   = (unsigned short*)(ws + 0xA00000);// 36*1024 B

  fps_kernel<<<16, 512, 0, stream>>>(points, outc);
  transpose_feats<<<1024, 256, 0, stream>>>(features, featsT);
  pack_w<<<36, 64, 0, stream>>>(w1, w2, w3, wpack);
  ball_query_kernel<<<256, 256, 0, stream>>>(points, outc, nidx);
  mlp_kernel<<<1024, 256, 0, stream>>>(points, outc, nidx, featsT, wpack,
                                       b1, g1, be1, b2, g2, be2, b3, g3, be3, outf);
}

// Round 3
// 1106.384 us; speedup vs baseline: 1.5698x; 1.3386x over previous
//
#include <hip/hip_runtime.h>
#include <math.h>

#define NPTS 4096
#define MC   1024
#define KNB  32

typedef __attribute__((ext_vector_type(8))) short bf16x8;
typedef __attribute__((ext_vector_type(4))) float f32x4;

__device__ __forceinline__ unsigned short f2bf(float f) {
  unsigned int u = __float_as_uint(f);
  u = u + 0x7fffu + ((u >> 16) & 1u);   // round-to-nearest-even
  return (unsigned short)(u >> 16);
}

// 64-bit-key DPP argmax step (keeps greater key). Key = (distbits<<32)|~idx,
// so max key == max dist with lowest-index tie-break.
template <int CTRL>
__device__ __forceinline__ void dpp_step64(unsigned int& hi, unsigned int& lo) {
  unsigned int ohi = (unsigned int)__builtin_amdgcn_update_dpp((int)hi, (int)hi, CTRL, 0xF, 0xF, false);
  unsigned int olo = (unsigned int)__builtin_amdgcn_update_dpp((int)lo, (int)lo, CTRL, 0xF, 0xF, false);
  if (ohi > hi || (ohi == hi && olo > lo)) { hi = ohi; lo = olo; }
}

// ---------------------------------------------------------------------------
// Kernel 1: farthest point sampling. One block per batch, 256 threads
// (4 waves), 16 points per lane IN REGISTERS — __launch_bounds__(256,1)
// relaxes the VGPR cap to 512 so nothing spills (round-2's VGPR=36 meant the
// compiler spilled the point arrays to scratch; that was the 1195us floor).
// Per iteration: dist update + per-lane argmax -> u64-key DPP wave argmax ->
// lane63 ds_write_b64 -> one barrier -> 4-key max -> coords via LDS broadcast.
// Bit-exact distances (no FMA contraction).
// ---------------------------------------------------------------------------
__global__ __launch_bounds__(256, 1) void fps_kernel(const float* __restrict__ points,
                                                     float* __restrict__ out_cent) {
  __shared__ float sx[NPTS], sy[NPTS], sz[NPTS];
  __shared__ __align__(16) unsigned long long skey[2][4];
  __shared__ float slog[3][MC];
  const int b = blockIdx.x, t = threadIdx.x;
  const int w = t >> 6, lane = t & 63;
  const float* pb = points + (size_t)b * 3 * NPTS;

  // stage points into LDS and registers; lane-owned idx for (k,c) = k*1024+t*4+c
  float fx[16], fy[16], fz[16], dist[16];
#pragma unroll
  for (int k = 0; k < 4; ++k) {
    float4 X = ((const float4*)pb)[k * 256 + t];
    float4 Y = ((const float4*)(pb + NPTS))[k * 256 + t];
    float4 Z = ((const float4*)(pb + 2 * NPTS))[k * 256 + t];
    ((float4*)sx)[k * 256 + t] = X;
    ((float4*)sy)[k * 256 + t] = Y;
    ((float4*)sz)[k * 256 + t] = Z;
    fx[k * 4 + 0] = X.x; fx[k * 4 + 1] = X.y; fx[k * 4 + 2] = X.z; fx[k * 4 + 3] = X.w;
    fy[k * 4 + 0] = Y.x; fy[k * 4 + 1] = Y.y; fy[k * 4 + 2] = Y.z; fy[k * 4 + 3] = Y.w;
    fz[k * 4 + 0] = Z.x; fz[k * 4 + 1] = Z.y; fz[k * 4 + 2] = Z.z; fz[k * 4 + 3] = Z.w;
  }
#pragma unroll
  for (int j = 0; j < 16; ++j) dist[j] = 1e10f;
  __syncthreads();

  float lx = sx[0], ly = sy[0], lz = sz[0];

  for (int i = 0; i < MC; ++i) {
    if (t == 0) { slog[0][i] = lx; slog[1][i] = ly; slog[2][i] = lz; }
    if (i == MC - 1) break;

    // distance update + per-lane argmax over 16 owned points.
    // Owned idx ascends with j=(k*4+c), so strict '>' keeps lowest idx on ties.
    float bv = -1.0f; int bi = 0;
#pragma unroll
    for (int k = 0; k < 4; ++k)
#pragma unroll
      for (int c = 0; c < 4; ++c) {
        int j = k * 4 + c;
        float dx = __fsub_rn(fx[j], lx);
        float dy = __fsub_rn(fy[j], ly);
        float dz = __fsub_rn(fz[j], lz);
        float d  = __fadd_rn(__fadd_rn(__fmul_rn(dx, dx), __fmul_rn(dy, dy)), __fmul_rn(dz, dz));
        float dm = fminf(dist[j], d);
        dist[j] = dm;
        if (dm > bv) { bv = dm; bi = k * 1024 + t * 4 + c; }
      }

    // wave64 argmax on packed key (value, ~idx); result lands in lane 63
    unsigned int hi = __float_as_uint(bv), lo = ~(unsigned int)bi;
    dpp_step64<0x111>(hi, lo);   // row_shr:1
    dpp_step64<0x112>(hi, lo);   // row_shr:2
    dpp_step64<0x114>(hi, lo);   // row_shr:4
    dpp_step64<0x118>(hi, lo);   // row_shr:8
    dpp_step64<0x142>(hi, lo);   // row_bcast:15
    dpp_step64<0x143>(hi, lo);   // row_bcast:31

    const int nb = i & 1;
    if (lane == 63) skey[nb][w] = ((unsigned long long)hi << 32) | lo;
    __syncthreads();

    // all threads: reduce the 4 wave keys (keys unique -> plain max)
    unsigned long long k0 = skey[nb][0], k1 = skey[nb][1];
    unsigned long long k2 = skey[nb][2], k3 = skey[nb][3];
    unsigned long long ka = (k0 > k1) ? k0 : k1;
    unsigned long long kb = (k2 > k3) ? k2 : k3;
    unsigned long long km = (ka > kb) ? ka : kb;
    const int sel = (int)(~(unsigned int)km);   // recover idx

    lx = sx[sel]; ly = sy[sel]; lz = sz[sel];
  }
  __syncthreads();
  // coalesced centroid output [3][1024] per batch
  float* oc = out_cent + (size_t)b * 3 * MC;
#pragma unroll
  for (int k = 0; k < 12; ++k) {
    int idx = t + k * 256;
    oc[idx] = ((const float*)slog)[idx];
  }
}

// ---------------------------------------------------------------------------
// Kernel 2: features [B,64,N] fp32 -> featsT [B,N,64] bf16 (tiled transpose)
// ---------------------------------------------------------------------------
__global__ __launch_bounds__(256) void transpose_feats(const float* __restrict__ feats,
                                                       unsigned short* __restrict__ featsT) {
  __shared__ float tile[64][65];
  const int blk = blockIdx.x;
  const int b = blk >> 6;
  const int n0 = (blk & 63) * 64;
  const int t = threadIdx.x;
  const float* src = feats + (size_t)b * 64 * NPTS;
  {
    const int n = t & 63, cbase = t >> 6;
#pragma unroll
    for (int j = 0; j < 16; ++j) {
      int c = cbase + j * 4;
      tile[c][n] = src[(size_t)c * NPTS + n0 + n];
    }
  }
  __syncthreads();
  {
    const int c = t & 63, nbase = t >> 6;
    unsigned short* dst = featsT + ((size_t)b * NPTS + n0) * 64;
#pragma unroll
    for (int j = 0; j < 16; ++j) {
      int n = nbase + j * 4;
      dst[(size_t)n * 64 + c] = f2bf(tile[c][n]);
    }
  }
}

// ---------------------------------------------------------------------------
// Kernel 3: pack W1/W2/W3 into MFMA B-fragment order (bf16), with the layer-1
// column remap: X cols 0..63 = gfeat (ref cols 3..66), 64..66 = local xyz,
// 67..95 = zero pad.
// ---------------------------------------------------------------------------
__global__ __launch_bounds__(64) void pack_w(const float* __restrict__ w1,
                                             const float* __restrict__ w2,
                                             const float* __restrict__ w3,
                                             unsigned short* __restrict__ wpack) {
  const int f = blockIdx.x, lane = threadIdx.x;
  int layer, kt, nt;
  if (f < 12)      { layer = 0; kt = f >> 2;        nt = f & 3; }
  else if (f < 20) { layer = 1; kt = (f - 12) >> 2; nt = (f - 12) & 3; }
  else             { layer = 2; kt = (f - 20) >> 3; nt = (f - 20) & 7; }
  const int o = nt * 16 + (lane & 15);
  unsigned short* dst = wpack + ((size_t)f * 64 + lane) * 8;
#pragma unroll
  for (int j = 0; j < 8; ++j) {
    int k = kt * 32 + (lane >> 4) * 8 + j;
    float x = 0.0f;
    if (layer == 0)      { if (k < 67) { int cin = (k < 64) ? (k + 3) : (k - 64); x = w1[o * 67 + cin]; } }
    else if (layer == 1) { x = w2[o * 64 + k]; }
    else                 { x = w3[o * 64 + k]; }
    dst[j] = f2bf(x);
  }
}

// ---------------------------------------------------------------------------
// Kernel 4: ball query. Centroids read from out_cent layout [B,3,MC].
// ---------------------------------------------------------------------------
__global__ __launch_bounds__(256) void ball_query_kernel(const float* __restrict__ points,
                                                         const float* __restrict__ cent,
                                                         int* __restrict__ nidx) {
  __shared__ float sx[NPTS], sy[NPTS], sz[NPTS];
  __shared__ int lists[4][KNB];
  const int b  = blockIdx.x >> 4;
  const int cb = blockIdx.x & 15;
  const int t = threadIdx.x;
  const float* pb = points + (size_t)b * 3 * NPTS;
#pragma unroll
  for (int j = 0; j < 4; ++j) {
    int i4 = t + j * 256;
    ((float4*)sx)[i4] = ((const float4*)pb)[i4];
    ((float4*)sy)[i4] = ((const float4*)(pb + NPTS))[i4];
    ((float4*)sz)[i4] = ((const float4*)(pb + 2 * NPTS))[i4];
  }
  __syncthreads();
  const int w = t >> 6, lane = t & 63;
  const float R2 = (float)(0.2 * 0.2);
  const float* cbp = cent + (size_t)b * 3 * MC;
  for (int cm = 0; cm < 16; ++cm) {
    const int m  = cb * 64 + w * 16 + cm;
    const int bm = b * MC + m;
    const float cx = cbp[m], cy = cbp[MC + m], cz = cbp[2 * MC + m];
    const float c2 = __fadd_rn(__fadd_rn(__fmul_rn(cx, cx), __fmul_rn(cy, cy)), __fmul_rn(cz, cz));
    int cnt = 0;
    for (int ch = 0; ch < 64; ++ch) {
      const int n = ch * 64 + lane;
      float x = sx[n], y = sy[n], z = sz[n];
      float p2  = __fadd_rn(__fadd_rn(__fmul_rn(x, x),  __fmul_rn(y, y)),  __fmul_rn(z, z));
      float dot = __fadd_rn(__fadd_rn(__fmul_rn(cx, x), __fmul_rn(cy, y)), __fmul_rn(cz, z));
      float d2  = __fsub_rn(__fadd_rn(c2, p2), __fmul_rn(2.0f, dot));
      bool hit = (d2 <= R2);
      unsigned long long msk = __ballot(hit);
      if (hit) {
        int pos = cnt + __popcll(msk & ((1ull << lane) - 1ull));
        if (pos < KNB) lists[w][pos] = n;
      }
      cnt += __popcll(msk);
      if (cnt >= KNB) break;
    }
    if (lane < KNB) {
      int first = lists[w][0];
      int v = (lane < cnt) ? lists[w][lane] : first;
      nidx[(size_t)bm * KNB + lane] = v;
    }
  }
}

// ---------------------------------------------------------------------------
// Kernel 5: fused gather + 3-layer MLP (bf16 MFMA 16x16x32) + maxpool.
// Hs is wave-private: no block barriers between layers, only
// __threadfence_block(). obuf stride 20 kills the 16-way bank conflict.
// ---------------------------------------------------------------------------
__global__ __launch_bounds__(256) void mlp_kernel(
    const float* __restrict__ points,
    const float* __restrict__ cent,
    const int* __restrict__ nidx,
    const unsigned short* __restrict__ featsT,
    const unsigned short* __restrict__ wpack,
    const float* __restrict__ b1, const float* __restrict__ g1, const float* __restrict__ be1,
    const float* __restrict__ b2, const float* __restrict__ g2, const float* __restrict__ be2,
    const float* __restrict__ b3, const float* __restrict__ g3, const float* __restrict__ be3,
    float* __restrict__ out) {
  __shared__ __align__(16) unsigned short Hs[4][2][32 * 72];
  __shared__ __align__(16) float obuf[128 * 20];
  const int t = threadIdx.x;
  const int w = t >> 6, lane = t & 63;
  const int r = lane & 15, q = lane >> 4;
  const float inv_s = 1.0f / sqrtf(1.0f + 1e-5f);

  float pb1[4], ps1[4], pe1[4], pb2[4], ps2[4], pe2[4], pb3[8], ps3[8], pe3[8];
#pragma unroll
  for (int nt = 0; nt < 4; ++nt) {
    int o = nt * 16 + r;
    pb1[nt] = b1[o]; ps1[nt] = g1[o] * inv_s; pe1[nt] = be1[o];
    pb2[nt] = b2[o]; ps2[nt] = g2[o] * inv_s; pe2[nt] = be2[o];
  }
#pragma unroll
  for (int nt = 0; nt < 8; ++nt) {
    int o = nt * 16 + r;
    pb3[nt] = b3[o]; ps3[nt] = g3[o] * inv_s; pe3[nt] = be3[o];
  }
  const int bm0 = blockIdx.x * 16;
  const int b   = bm0 >> 10;
  const int m0  = bm0 & 1023;
  const float* ptsb = points + (size_t)b * 3 * NPTS;
  const float* cbp  = cent + (size_t)b * 3 * MC;

  for (int it = 0; it < 4; ++it) {
    const int ml = it * 4 + w;
    const int bm = bm0 + ml;
    const int m  = bm & 1023;
    const int n0 = nidx[(size_t)bm * KNB + r];
    const int n1 = nidx[(size_t)bm * KNB + 16 + r];
    const float cx = cbp[m], cy = cbp[MC + m], cz = cbp[2 * MC + m];

    // ---- layer 1 ----
    bf16x8 aF[2][2];
#pragma unroll
    for (int mt = 0; mt < 2; ++mt) {
      int n = mt ? n1 : n0;
      const unsigned short* rowp = featsT + ((size_t)b * NPTS + n) * 64 + q * 8;
      aF[mt][0] = *(const bf16x8*)(rowp);
      aF[mt][1] = *(const bf16x8*)(rowp + 32);
    }
    bf16x8 aL[2];
#pragma unroll
    for (int mt = 0; mt < 2; ++mt) {
      bf16x8 a = {0, 0, 0, 0, 0, 0, 0, 0};
      if (q == 0) {
        int n = mt ? n1 : n0;
        a[0] = (short)f2bf(ptsb[n] - cx);
        a[1] = (short)f2bf(ptsb[NPTS + n] - cy);
        a[2] = (short)f2bf(ptsb[2 * NPTS + n] - cz);
      }
      aL[mt] = a;
    }
    f32x4 acc1[2][4];
#pragma unroll
    for (int mt = 0; mt < 2; ++mt)
#pragma unroll
      for (int nt = 0; nt < 4; ++nt) acc1[mt][nt] = (f32x4){0.f, 0.f, 0.f, 0.f};
#pragma unroll
    for (int kt = 0; kt < 3; ++kt) {
#pragma unroll
      for (int nt = 0; nt < 4; ++nt) {
        bf16x8 wf = *(const bf16x8*)(wpack + ((size_t)(kt * 4 + nt) * 64 + lane) * 8);
#pragma unroll
        for (int mt = 0; mt < 2; ++mt) {
          bf16x8 a = (kt < 2) ? aF[mt][kt] : aL[mt];
          acc1[mt][nt] = __builtin_amdgcn_mfma_f32_16x16x32_bf16(a, wf, acc1[mt][nt], 0, 0, 0);
        }
      }
    }
#pragma unroll
    for (int mt = 0; mt < 2; ++mt)
#pragma unroll
      for (int nt = 0; nt < 4; ++nt)
#pragma unroll
        for (int rr = 0; rr < 4; ++rr) {
          float y = (acc1[mt][nt][rr] + pb1[nt]) * ps1[nt] + pe1[nt];
          y = fmaxf(y, 0.0f);
          Hs[w][0][(mt * 16 + q * 4 + rr) * 72 + nt * 16 + r] = f2bf(y);
        }
    __threadfence_block();

    // ---- layer 2 ----
    f32x4 acc2[2][4];
#pragma unroll
    for (int mt = 0; mt < 2; ++mt)
#pragma unroll
      for (int nt = 0; nt < 4; ++nt) acc2[mt][nt] = (f32x4){0.f, 0.f, 0.f, 0.f};
#pragma unroll
    for (int kt = 0; kt < 2; ++kt) {
      bf16x8 a0 = *(const bf16x8*)&Hs[w][0][(0 * 16 + r) * 72 + kt * 32 + q * 8];
      bf16x8 a1 = *(const bf16x8*)&Hs[w][0][(1 * 16 + r) * 72 + kt * 32 + q * 8];
#pragma unroll
      for (int nt = 0; nt < 4; ++nt) {
        bf16x8 wf = *(const bf16x8*)(wpack + ((size_t)(12 + kt * 4 + nt) * 64 + lane) * 8);
        acc2[0][nt] = __builtin_amdgcn_mfma_f32_16x16x32_bf16(a0, wf, acc2[0][nt], 0, 0, 0);
        acc2[1][nt] = __builtin_amdgcn_mfma_f32_16x16x32_bf16(a1, wf, acc2[1][nt], 0, 0, 0);
      }
    }
#pragma unroll
    for (int mt = 0; mt < 2; ++mt)
#pragma unroll
      for (int nt = 0; nt < 4; ++nt)
#pragma unroll
        for (int rr = 0; rr < 4; ++rr) {
          float y = (acc2[mt][nt][rr] + pb2[nt]) * ps2[nt] + pe2[nt];
          y = fmaxf(y, 0.0f);
          Hs[w][1][(mt * 16 + q * 4 + rr) * 72 + nt * 16 + r] = f2bf(y);
        }
    __threadfence_block();

    // ---- layer 3 + maxpool ----
    f32x4 acc3[2][8];
#pragma unroll
    for (int mt = 0; mt < 2; ++mt)
#pragma unroll
      for (int nt = 0; nt < 8; ++nt) acc3[mt][nt] = (f32x4){0.f, 0.f, 0.f, 0.f};
#pragma unroll
    for (int kt = 0; kt < 2; ++kt) {
      bf16x8 a0 = *(const bf16x8*)&Hs[w][1][(0 * 16 + r) * 72 + kt * 32 + q * 8];
      bf16x8 a1 = *(const bf16x8*)&Hs[w][1][(1 * 16 + r) * 72 + kt * 32 + q * 8];
#pragma unroll
      for (int nt = 0; nt < 8; ++nt) {
        bf16x8 wf = *(const bf16x8*)(wpack + ((size_t)(20 + kt * 8 + nt) * 64 + lane) * 8);
        acc3[0][nt] = __builtin_amdgcn_mfma_f32_16x16x32_bf16(a0, wf, acc3[0][nt], 0, 0, 0);
        acc3[1][nt] = __builtin_amdgcn_mfma_f32_16x16x32_bf16(a1, wf, acc3[1][nt], 0, 0, 0);
      }
    }
#pragma unroll
    for (int nt = 0; nt < 8; ++nt) {
      float pm = 0.0f;   // relu outputs are >= 0
#pragma unroll
      for (int mt = 0; mt < 2; ++mt)
#pragma unroll
        for (int rr = 0; rr < 4; ++rr) {
          float y = (acc3[mt][nt][rr] + pb3[nt]) * ps3[nt] + pe3[nt];
          y = fmaxf(y, 0.0f);
          pm = fmaxf(pm, y);
        }
      pm = fmaxf(pm, __shfl_xor(pm, 16));
      pm = fmaxf(pm, __shfl_xor(pm, 32));
      if (q == 0) obuf[(nt * 16 + r) * 20 + ml] = pm;
    }
    __threadfence_block();
  }
  __syncthreads();
  // coalesced-ish store: thread t -> channel t>>1, half (t&1)*8
  {
    const int ch = t >> 1, mh = (t & 1) * 8;
    float4 u0 = *(const float4*)&obuf[ch * 20 + mh];
    float4 u1 = *(const float4*)&obuf[ch * 20 + mh + 4];
    float* outp = out + ((size_t)b * 128 + ch) * 1024 + m0 + mh;
    *(float4*)(outp)     = u0;
    *(float4*)(outp + 4) = u1;
  }
}

// ---------------------------------------------------------------------------
extern "C" void kernel_launch(void* const* d_in, const int* in_sizes, int n_in,
                              void* d_out, int out_size, void* d_ws, size_t ws_size,
                              hipStream_t stream) {
  (void)in_sizes; (void)n_in; (void)out_size; (void)ws_size;
  const float* points   = (const float*)d_in[0];
  const float* features = (const float*)d_in[1];
  const float* w1  = (const float*)d_in[2];
  const float* b1  = (const float*)d_in[3];
  const float* g1  = (const float*)d_in[4];
  const float* be1 = (const float*)d_in[5];
  const float* w2  = (const float*)d_in[6];
  const float* b2  = (const float*)d_in[7];
  const float* g2  = (const float*)d_in[8];
  const float* be2 = (const float*)d_in[9];
  const float* w3  = (const float*)d_in[10];
  const float* b3  = (const float*)d_in[11];
  const float* g3  = (const float*)d_in[12];
  const float* be3 = (const float*)d_in[13];

  float* outc = (float*)d_out;                  // centroids [16,3,1024]
  float* outf = outc + 16 * 3 * 1024;           // features  [16,128,1024]

  char* ws = (char*)d_ws;
  int*            nidx    = (int*)(ws);                      // 16384*32*4  = 2 MiB
  unsigned short* featsT  = (unsigned short*)(ws + 0x200000);// 16*4096*64*2= 8 MiB
  unsigned short* wpack   = (unsigned short*)(ws + 0xA00000);// 36*1024 B

  fps_kernel<<<16, 256, 0, stream>>>(points, outc);
  transpose_feats<<<1024, 256, 0, stream>>>(features, featsT);
  pack_w<<<36, 64, 0, stream>>>(w1, w2, w3, wpack);
  ball_query_kernel<<<256, 256, 0, stream>>>(points, outc, nidx);
  mlp_kernel<<<1024, 256, 0, stream>>>(points, outc, nidx, featsT, wpack,
                                       b1, g1, be1, b2, g2, be2, b3, g3, be3, outf);
}